// Round 3
// baseline (423.789 us; speedup 1.0000x reference)
//
#include <hip/hip_runtime.h>
#include <math.h>

#define HIDC 64
#define HD 512  // combined xl|xr channels per node (bf16)

typedef unsigned int uint32;
using short8 = __attribute__((ext_vector_type(8))) short;
using f32x4 = __attribute__((ext_vector_type(4))) float;

__device__ inline float ubits(uint32 u) { return __builtin_bit_cast(float, u); }
__device__ inline unsigned short f2bf(float x) {
  uint32 u = __builtin_bit_cast(uint32, x);
  return (unsigned short)((u + 0x7fffu + ((u >> 16) & 1u)) >> 16);
}

template <int CTRL>
__device__ inline float dpp_add(float x) {
  int xi = __builtin_bit_cast(int, x);
  int s = __builtin_amdgcn_update_dpp(0, xi, CTRL, 0xf, 0xf, true);
  return x + __builtin_bit_cast(float, s);
}
#define QUAD_XOR1 0xB1  // quad_perm [1,0,3,2]
#define QUAD_XOR2 0x4E  // quad_perm [2,3,0,1]

// ---------------- CSR build ----------------
__global__ void count_kernel(const int* __restrict__ ei, int E, int N,
                             int* __restrict__ counts) {
  int e = blockIdx.x * blockDim.x + threadIdx.x;
  int etot = E + N;
  if (e >= etot) return;
  int dst = (e < E) ? ei[E + e] : (e - E);
  atomicAdd(&counts[dst], 1);
}

__global__ __launch_bounds__(1024) void scan_kernel(const int* __restrict__ counts,
                                                    int* __restrict__ row_start, int n) {
  __shared__ int wsum[16];
  __shared__ int carry;
  int tid = threadIdx.x;
  int lane = tid & 63, wid = tid >> 6;
  if (tid == 0) { carry = 0; row_start[0] = 0; }
  __syncthreads();
  for (int base = 0; base < n; base += 4096) {
    int i0 = base + tid * 4;
    int4 c = make_int4(0, 0, 0, 0);
    if (i0 + 3 < n) c = *(const int4*)&counts[i0];
    else {
      if (i0 + 0 < n) c.x = counts[i0 + 0];
      if (i0 + 1 < n) c.y = counts[i0 + 1];
      if (i0 + 2 < n) c.z = counts[i0 + 2];
      if (i0 + 3 < n) c.w = counts[i0 + 3];
    }
    int s1 = c.x + c.y, s2 = s1 + c.z, s3 = s2 + c.w;
    int x = s3;
#pragma unroll
    for (int offd = 1; offd < 64; offd <<= 1) {
      int t = __shfl_up(x, offd, 64);
      if (lane >= offd) x += t;
    }
    if (lane == 63) wsum[wid] = x;
    __syncthreads();
    if (wid == 0) {
      int v2 = (lane < 16) ? wsum[lane] : 0;
#pragma unroll
      for (int offd = 1; offd < 16; offd <<= 1) {
        int t = __shfl_up(v2, offd, 64);
        if (lane >= offd) v2 += t;
      }
      if (lane < 16) wsum[lane] = v2;
    }
    __syncthreads();
    int pre = (wid > 0 ? wsum[wid - 1] : 0) + carry + (x - s3);
    if (i0 + 0 < n) row_start[i0 + 1] = pre + c.x;
    if (i0 + 1 < n) row_start[i0 + 2] = pre + s1;
    if (i0 + 2 < n) row_start[i0 + 3] = pre + s2;
    if (i0 + 3 < n) row_start[i0 + 4] = pre + s3;
    __syncthreads();
    if (tid == 0) carry += wsum[15];
    __syncthreads();
  }
}

__global__ void scatter_kernel(const int* __restrict__ ei, int E, int N,
                               const int* __restrict__ row_start,
                               int* __restrict__ cursor, int* __restrict__ csr_src) {
  int e = blockIdx.x * blockDim.x + threadIdx.x;
  int etot = E + N;
  if (e >= etot) return;
  int src, dst;
  if (e < E) { src = ei[e]; dst = ei[E + e]; } else { src = e - E; dst = src; }
  int pos = row_start[dst] + atomicAdd(&cursor[dst], 1);
  csr_src[pos] = src;
}

// ---------------- fused fp32 -> bf16 pack for x + all 4 weights ----------------
__global__ void pack_all(const float* __restrict__ x,
                         const float* __restrict__ Wl1, const float* __restrict__ Wr1,
                         const float* __restrict__ Wl2, const float* __restrict__ Wr2,
                         unsigned short* __restrict__ xb, unsigned short* __restrict__ Wc1,
                         unsigned short* __restrict__ Wc2, int n4x) {
  int i = blockIdx.x * blockDim.x + threadIdx.x;
  const float* src;
  unsigned short* dst;
  int local;
  if (i < n4x) { src = x; dst = xb; local = i; }
  else {
    int j = i - n4x;
    if (j < 8192) { src = Wl1; dst = Wc1; local = j; }
    else if (j < 16384) { src = Wr1; dst = Wc1 + 32768; local = j - 8192; }
    else if (j < 20480) { src = Wl2; dst = Wc2; local = j - 16384; }
    else if (j < 24576) { src = Wr2; dst = Wc2 + 16384; local = j - 20480; }
    else return;
  }
  float4 v = ((const float4*)src)[local];
  ushort4 o;
  o.x = f2bf(v.x); o.y = f2bf(v.y); o.z = f2bf(v.z); o.w = f2bf(v.w);
  ((ushort4*)dst)[local] = o;
}

// ---------------- MFMA GEMM: C[M,512](bf16) = A[M,K](bf16) @ W[512,K](bf16)^T + bias
#define MFMA16 __builtin_amdgcn_mfma_f32_16x16x32_bf16
template <int K>
__global__ __launch_bounds__(256, 2) void mfma_gemm(
    const unsigned short* __restrict__ A, const unsigned short* __restrict__ W,
    const float* __restrict__ bl, const float* __restrict__ br,
    unsigned short* __restrict__ C, int M) {
  int lane = threadIdx.x & 63;
  int wv = threadIdx.x >> 6;
  int m0 = blockIdx.x * 256 + wv * 64;
  int n0 = blockIdx.y * 64;
  int lr = lane & 15, lk = (lane >> 4) * 8;
  const float* bp = (n0 < 256) ? bl : br;
  int nb = n0 & 255;

  short8 bfrag[4][K / 32];
#pragma unroll
  for (int nf = 0; nf < 4; ++nf)
#pragma unroll
    for (int ks = 0; ks < K / 32; ++ks)
      bfrag[nf][ks] = *(const short8*)&W[(size_t)(n0 + nf * 16 + lr) * K + ks * 32 + lk];

  f32x4 acc[4][4];
#pragma unroll
  for (int i = 0; i < 4; ++i)
#pragma unroll
    for (int j = 0; j < 4; ++j) acc[i][j] = (f32x4){0.f, 0.f, 0.f, 0.f};

#pragma unroll
  for (int mf = 0; mf < 4; ++mf) {
    int mr = m0 + mf * 16 + lr;
    int mrc = mr < M ? mr : 0;
    short8 afrag[K / 32];
#pragma unroll
    for (int ks = 0; ks < K / 32; ++ks)
      afrag[ks] = *(const short8*)&A[(size_t)mrc * K + ks * 32 + lk];
#pragma unroll
    for (int ks = 0; ks < K / 32; ++ks)
#pragma unroll
      for (int nf = 0; nf < 4; ++nf)
        acc[mf][nf] = MFMA16(afrag[ks], bfrag[nf][ks], acc[mf][nf], 0, 0, 0);
  }

  int cr = (lane >> 4) * 4;
#pragma unroll
  for (int mf = 0; mf < 4; ++mf) {
#pragma unroll
    for (int r = 0; r < 4; ++r) {
      int m = m0 + mf * 16 + cr + r;
      if (m < M) {
#pragma unroll
        for (int nf = 0; nf < 4; ++nf) {
          int n = n0 + nf * 16 + lr;
          float v = acc[mf][nf][r] + bp[nb + nf * 16 + lr];
          C[(size_t)m * HD + n] = f2bf(v);
        }
      }
    }
  }
}

// ---------------- Fused GATv2: 4 edges/wave, 16ch/lane ----------------
// Wave = node v. row = lane>>4 owns edge slot; col = lane&15 owns ch col*16..+15.
// Head of a lane = col>>2 (64 ch per head = 4 cols). Score reduce = 2 quad DPP ops.
template <bool LAST>
__global__ __launch_bounds__(256, 4) void gat_kernel(
    const unsigned short* __restrict__ xlr,
    const float* __restrict__ att, const float* __restrict__ bias,
    const float* __restrict__ gamma, const float* __restrict__ beta,
    const int* __restrict__ row_start, const int* __restrict__ csr_src,
    const float* __restrict__ Wh1, const float* __restrict__ bh1,
    const float* __restrict__ Wh2, const float* __restrict__ bh2,
    void* __restrict__ outp, int N) {
  __shared__ float sh[4][96];
  int wid = threadIdx.x >> 6;
  int lane = threadIdx.x & 63;
  int v = blockIdx.x * 4 + wid;
  if (v >= N) return;
  int row = lane >> 4, col = lane & 15;
  int ch0 = col * 16;

  // xr for this lane's 16 channels
  float xr[16];
  {
    uint4 q0 = *(const uint4*)&xlr[(size_t)v * HD + 256 + ch0];
    uint4 q1 = *(const uint4*)&xlr[(size_t)v * HD + 256 + ch0 + 8];
    uint32 w[8] = {q0.x, q0.y, q0.z, q0.w, q1.x, q1.y, q1.z, q1.w};
#pragma unroll
    for (int j = 0; j < 8; ++j) {
      xr[2 * j] = ubits(w[j] << 16);
      xr[2 * j + 1] = ubits(w[j] & 0xffff0000u);
    }
  }
  float at[16];
#pragma unroll
  for (int j = 0; j < 4; ++j) {
    float4 a4 = *(const float4*)&att[ch0 + 4 * j];
    at[4 * j] = a4.x; at[4 * j + 1] = a4.y; at[4 * j + 2] = a4.z; at[4 * j + 3] = a4.w;
  }

  float acc[16];
#pragma unroll
  for (int i = 0; i < 16; ++i) acc[i] = 0.f;
  float ssum = 0.f;

  auto group = [&](uint4 q0, uint4 q1, bool valid) {
    uint32 w[8] = {q0.x, q0.y, q0.z, q0.w, q1.x, q1.y, q1.z, q1.w};
    float t[16];
    float p6 = 0.f, p4 = 0.f;
#pragma unroll
    for (int j = 0; j < 8; ++j) {
      float lo = ubits(w[j] << 16);
      float hi = ubits(w[j] & 0xffff0000u);
      t[2 * j] = lo + xr[2 * j];
      t[2 * j + 1] = hi + xr[2 * j + 1];
      p6 = fmaf(at[2 * j], t[2 * j], p6);
      p4 = fmaf(at[2 * j], fabsf(t[2 * j]), p4);
      p6 = fmaf(at[2 * j + 1], t[2 * j + 1], p6);
      p4 = fmaf(at[2 * j + 1], fabsf(t[2 * j + 1]), p4);
    }
    // leaky(t)*att summed = 0.6*p6 + 0.4*p4; reduce over quad (head = 64ch = 4 lanes)
    float sc = fmaf(0.4f, p4, 0.6f * p6);
    sc = dpp_add<QUAD_XOR1>(sc);
    sc = dpp_add<QUAD_XOR2>(sc);
    float p = __expf(sc);  // scores O(1): softmax shift not needed
    p = valid ? p : 0.f;
    ssum += p;
#pragma unroll
    for (int i = 0; i < 16; ++i) acc[i] = fmaf(p, t[i], acc[i]);  // sum p*t; fix later
  };

  int rs = row_start[v], re = row_start[v + 1];
  for (int base = rs; base < re; base += 8) {
    int iA = base + row;
    int cA = iA < re ? iA : re - 1;
    int sA = csr_src[cA];
    const uint4* pA = (const uint4*)&xlr[(size_t)sA * HD + ch0];
    uint4 a0 = pA[0], a1 = pA[1];
    bool doB = (base + 4) < re;
    if (doB) {
      int iB = base + 4 + row;
      int cB = iB < re ? iB : re - 1;
      int sB = csr_src[cB];
      const uint4* pB = (const uint4*)&xlr[(size_t)sB * HD + ch0];
      uint4 b0 = pB[0], b1 = pB[1];
      group(a0, a1, iA < re);
      group(b0, b1, iB < re);
    } else {
      group(a0, a1, iA < re);
    }
  }

  // cross-row ssum (per-head totals)
  ssum += __shfl_xor(ssum, 16);
  ssum += __shfl_xor(ssum, 32);
  float inv = 1.f / ssum;  // self-loop guarantees > 0

  // cross-row acc, then hv = acc*inv - xr  (undo the +xr folded into t)
  float hv[16];
#pragma unroll
  for (int i = 0; i < 16; ++i) {
    float a = acc[i];
    a += __shfl_xor(a, 16);
    a += __shfl_xor(a, 32);
    hv[i] = fmaf(a, inv, -xr[i]);
  }
  // head mean over lanes col, col^4, col^8, col^12 (same col&3)
#pragma unroll
  for (int i = 0; i < 16; ++i) {
    hv[i] += __shfl_xor(hv[i], 4);
    hv[i] += __shfl_xor(hv[i], 8);
  }
  int jb = (col & 3) * 16;  // output channel base (0..63), valid in every quad
#pragma unroll
  for (int j = 0; j < 4; ++j) {
    float4 b4 = *(const float4*)&bias[jb + 4 * j];
    hv[4 * j] = 0.25f * hv[4 * j] + b4.x;
    hv[4 * j + 1] = 0.25f * hv[4 * j + 1] + b4.y;
    hv[4 * j + 2] = 0.25f * hv[4 * j + 2] + b4.z;
    hv[4 * j + 3] = 0.25f * hv[4 * j + 3] + b4.w;
  }
  // LayerNorm over 64 ch: lane holds 16, quad (col&3 = 0..3) holds all 64
  float psum = 0.f, psq = 0.f;
#pragma unroll
  for (int i = 0; i < 16; ++i) { psum += hv[i]; psq = fmaf(hv[i], hv[i], psq); }
  psum = dpp_add<QUAD_XOR1>(psum); psum = dpp_add<QUAD_XOR2>(psum);
  psq = dpp_add<QUAD_XOR1>(psq); psq = dpp_add<QUAD_XOR2>(psq);
  float mean = psum * (1.f / 64.f);
  float var = psq * (1.f / 64.f) - mean * mean;
  float rstd = rsqrtf(var + 1e-5f);
  float y[16];
#pragma unroll
  for (int j = 0; j < 4; ++j) {
    float4 g4 = *(const float4*)&gamma[jb + 4 * j];
    float4 be4 = *(const float4*)&beta[jb + 4 * j];
    y[4 * j] = (hv[4 * j] - mean) * rstd * g4.x + be4.x;
    y[4 * j + 1] = (hv[4 * j + 1] - mean) * rstd * g4.y + be4.y;
    y[4 * j + 2] = (hv[4 * j + 2] - mean) * rstd * g4.z + be4.z;
    y[4 * j + 3] = (hv[4 * j + 3] - mean) * rstd * g4.w + be4.w;
  }
#pragma unroll
  for (int i = 0; i < 16; ++i) y[i] = y[i] > 0.f ? y[i] : expm1f(y[i]);

  if (!LAST) {
    if (lane < 4) {  // lanes 0-3 hold out ch lane*16..+15
      uint32 o[8];
#pragma unroll
      for (int j = 0; j < 8; ++j)
        o[j] = (uint32)f2bf(y[2 * j]) | ((uint32)f2bf(y[2 * j + 1]) << 16);
      unsigned short* h1 = (unsigned short*)outp;
      *(uint4*)&h1[(size_t)v * HIDC + lane * 16] = make_uint4(o[0], o[1], o[2], o[3]);
      *(uint4*)&h1[(size_t)v * HIDC + lane * 16 + 8] = make_uint4(o[4], o[5], o[6], o[7]);
    }
  } else {
    float* out = (float*)outp;
    if (lane < 4) {
#pragma unroll
      for (int i = 0; i < 16; ++i) sh[wid][lane * 16 + i] = y[i];
    }
    if (lane < 32) {  // same-wave LDS ordering; waves independent
      float a = bh1[lane];
      const float* wrow = &Wh1[lane * 64];
#pragma unroll 8
      for (int k = 0; k < 64; ++k) a += sh[wid][k] * wrow[k];
      sh[wid][64 + lane] = fmaxf(a, 0.f);
    }
    if (lane < 2) {
      float o = bh2[lane];
      const float* wrow = &Wh2[lane * 32];
#pragma unroll 8
      for (int k = 0; k < 32; ++k) o += sh[wid][64 + k] * wrow[k];
      out[(size_t)v * 2 + lane] = o;
    }
  }
}

// ---------------- launch ----------------
extern "C" void kernel_launch(void* const* d_in, const int* in_sizes, int n_in,
                              void* d_out, int out_size, void* d_ws, size_t ws_size,
                              hipStream_t stream) {
  const float* x = (const float*)d_in[0];
  const int* ei = (const int*)d_in[1];
  const float* Wl1 = (const float*)d_in[2]; const float* bl1 = (const float*)d_in[3];
  const float* Wr1 = (const float*)d_in[4]; const float* br1 = (const float*)d_in[5];
  const float* att1 = (const float*)d_in[6]; const float* bias1 = (const float*)d_in[7];
  const float* Wl2 = (const float*)d_in[8]; const float* bl2 = (const float*)d_in[9];
  const float* Wr2 = (const float*)d_in[10]; const float* br2 = (const float*)d_in[11];
  const float* att2 = (const float*)d_in[12]; const float* bias2 = (const float*)d_in[13];
  const float* g1 = (const float*)d_in[14]; const float* be1 = (const float*)d_in[15];
  const float* g2 = (const float*)d_in[16]; const float* be2 = (const float*)d_in[17];
  const float* Wh1 = (const float*)d_in[18]; const float* bh1 = (const float*)d_in[19];
  const float* Wh2 = (const float*)d_in[20]; const float* bh2 = (const float*)d_in[21];
  float* out = (float*)d_out;

  int N = in_sizes[0] / 128;
  int E = in_sizes[1] / 2;
  int ET = E + N;

  char* ws = (char*)d_ws;
  size_t off = 0;
  auto alloc = [&](size_t bytes) {
    void* p = ws + off;
    off += (bytes + 255) & ~(size_t)255;
    return p;
  };
  unsigned short* xlr = (unsigned short*)alloc((size_t)N * HD * 2);
  unsigned short* xb  = (unsigned short*)alloc((size_t)N * 128 * 2);
  unsigned short* h1b = (unsigned short*)alloc((size_t)N * HIDC * 2);
  unsigned short* Wc1 = (unsigned short*)alloc((size_t)512 * 128 * 2);
  unsigned short* Wc2 = (unsigned short*)alloc((size_t)512 * 64 * 2);
  int* row_start = (int*)alloc((size_t)(N + 1) * 4);
  int* counts = (int*)alloc((size_t)N * 4);
  int* cursor = (int*)alloc((size_t)N * 4);
  int* csr = (int*)alloc((size_t)ET * 4);

  hipMemsetAsync(counts, 0, (size_t)N * 4, stream);
  hipMemsetAsync(cursor, 0, (size_t)N * 4, stream);

  int eb = (ET + 255) / 256;
  count_kernel<<<eb, 256, 0, stream>>>(ei, E, N, counts);
  scan_kernel<<<1, 1024, 0, stream>>>(counts, row_start, N);
  scatter_kernel<<<eb, 256, 0, stream>>>(ei, E, N, row_start, cursor, csr);

  int n4x = N * 128 / 4;
  int tot4 = n4x + 24576;
  pack_all<<<(tot4 + 255) / 256, 256, 0, stream>>>(x, Wl1, Wr1, Wl2, Wr2,
                                                   xb, Wc1, Wc2, n4x);

  dim3 gg((N + 255) / 256, 8);
  mfma_gemm<128><<<gg, 256, 0, stream>>>(xb, Wc1, bl1, br1, xlr, N);

  int gb = (N + 3) / 4;
  gat_kernel<false><<<gb, 256, 0, stream>>>(xlr, att1, bias1, g1, be1,
                                            row_start, csr, nullptr, nullptr,
                                            nullptr, nullptr, h1b, N);

  mfma_gemm<64><<<gg, 256, 0, stream>>>(h1b, Wc2, bl2, br2, xlr, N);

  gat_kernel<true><<<gb, 256, 0, stream>>>(xlr, att2, bias2, g2, be2,
                                           row_start, csr, Wh1, bh1, Wh2, bh2,
                                           out, N);
}

// Round 5
// 363.566 us; speedup vs baseline: 1.1656x; 1.1656x over previous
//
#include <hip/hip_runtime.h>
#include <math.h>

#define HIDC 64
#define HD 512  // combined xl|xr channels per node (bf16)

typedef unsigned int uint32;
using short8 = __attribute__((ext_vector_type(8))) short;
using f32x4 = __attribute__((ext_vector_type(4))) float;

__device__ inline float ubits(uint32 u) { return __builtin_bit_cast(float, u); }
__device__ inline unsigned short f2bf(float x) {
  uint32 u = __builtin_bit_cast(uint32, x);
  return (unsigned short)((u + 0x7fffu + ((u >> 16) & 1u)) >> 16);
}

template <int CTRL>
__device__ inline float dpp_add(float x) {
  int xi = __builtin_bit_cast(int, x);
  int s = __builtin_amdgcn_update_dpp(0, xi, CTRL, 0xf, 0xf, true);
  return x + __builtin_bit_cast(float, s);
}

// ---------------- CSR build ----------------
__global__ void count_kernel(const int* __restrict__ ei, int E, int N,
                             int* __restrict__ counts) {
  int e = blockIdx.x * blockDim.x + threadIdx.x;
  int etot = E + N;
  if (e >= etot) return;
  int dst = (e < E) ? ei[E + e] : (e - E);
  atomicAdd(&counts[dst], 1);
}

__global__ __launch_bounds__(1024) void scan_kernel(const int* __restrict__ counts,
                                                    int* __restrict__ row_start, int n) {
  __shared__ int wsum[16];
  __shared__ int carry;
  int tid = threadIdx.x;
  int lane = tid & 63, wid = tid >> 6;
  if (tid == 0) { carry = 0; row_start[0] = 0; }
  __syncthreads();
  for (int base = 0; base < n; base += 4096) {
    int i0 = base + tid * 4;
    int4 c = make_int4(0, 0, 0, 0);
    if (i0 + 3 < n) c = *(const int4*)&counts[i0];
    else {
      if (i0 + 0 < n) c.x = counts[i0 + 0];
      if (i0 + 1 < n) c.y = counts[i0 + 1];
      if (i0 + 2 < n) c.z = counts[i0 + 2];
      if (i0 + 3 < n) c.w = counts[i0 + 3];
    }
    int s1 = c.x + c.y, s2 = s1 + c.z, s3 = s2 + c.w;
    int x = s3;
#pragma unroll
    for (int offd = 1; offd < 64; offd <<= 1) {
      int t = __shfl_up(x, offd, 64);
      if (lane >= offd) x += t;
    }
    if (lane == 63) wsum[wid] = x;
    __syncthreads();
    if (wid == 0) {
      int v2 = (lane < 16) ? wsum[lane] : 0;
#pragma unroll
      for (int offd = 1; offd < 16; offd <<= 1) {
        int t = __shfl_up(v2, offd, 64);
        if (lane >= offd) v2 += t;
      }
      if (lane < 16) wsum[lane] = v2;
    }
    __syncthreads();
    int pre = (wid > 0 ? wsum[wid - 1] : 0) + carry + (x - s3);
    if (i0 + 0 < n) row_start[i0 + 1] = pre + c.x;
    if (i0 + 1 < n) row_start[i0 + 2] = pre + s1;
    if (i0 + 2 < n) row_start[i0 + 3] = pre + s2;
    if (i0 + 3 < n) row_start[i0 + 4] = pre + s3;
    __syncthreads();
    if (tid == 0) carry += wsum[15];
    __syncthreads();
  }
}

__global__ void scatter_kernel(const int* __restrict__ ei, int E, int N,
                               const int* __restrict__ row_start,
                               int* __restrict__ cursor, int* __restrict__ csr_src) {
  int e = blockIdx.x * blockDim.x + threadIdx.x;
  int etot = E + N;
  if (e >= etot) return;
  int src, dst;
  if (e < E) { src = ei[e]; dst = ei[E + e]; } else { src = e - E; dst = src; }
  int pos = row_start[dst] + atomicAdd(&cursor[dst], 1);
  csr_src[pos] = src;
}

// ---------------- fused fp32 -> bf16 pack for x + all 4 weights ----------------
__global__ void pack_all(const float* __restrict__ x,
                         const float* __restrict__ Wl1, const float* __restrict__ Wr1,
                         const float* __restrict__ Wl2, const float* __restrict__ Wr2,
                         unsigned short* __restrict__ xb, unsigned short* __restrict__ Wc1,
                         unsigned short* __restrict__ Wc2, int n4x) {
  int i = blockIdx.x * blockDim.x + threadIdx.x;
  const float* src;
  unsigned short* dst;
  int local;
  if (i < n4x) { src = x; dst = xb; local = i; }
  else {
    int j = i - n4x;
    if (j < 8192) { src = Wl1; dst = Wc1; local = j; }
    else if (j < 16384) { src = Wr1; dst = Wc1 + 32768; local = j - 8192; }
    else if (j < 20480) { src = Wl2; dst = Wc2; local = j - 16384; }
    else if (j < 24576) { src = Wr2; dst = Wc2 + 16384; local = j - 20480; }
    else return;
  }
  float4 v = ((const float4*)src)[local];
  ushort4 o;
  o.x = f2bf(v.x); o.y = f2bf(v.y); o.z = f2bf(v.z); o.w = f2bf(v.w);
  ((ushort4*)dst)[local] = o;
}

// ---------------- MFMA GEMM: C[M,512](bf16) = A[M,K](bf16) @ W[512,K](bf16)^T + bias
// Block = 4 waves sharing ONE 64-row A tile (L1 reuse); wave wv covers n0=y*256+wv*64.
#define MFMA16 __builtin_amdgcn_mfma_f32_16x16x32_bf16
template <int K>
__global__ __launch_bounds__(256, 2) void mfma_gemm(
    const unsigned short* __restrict__ A, const unsigned short* __restrict__ W,
    const float* __restrict__ bl, const float* __restrict__ br,
    unsigned short* __restrict__ C, int M) {
  int lane = threadIdx.x & 63;
  int wv = threadIdx.x >> 6;
  int m0 = blockIdx.x * 64;
  int n0 = blockIdx.y * 256 + wv * 64;
  int lr = lane & 15, lk = (lane >> 4) * 8;
  const float* bp = (n0 < 256) ? bl : br;
  int nb = n0 & 255;

  short8 bfrag[4][K / 32];
#pragma unroll
  for (int nf = 0; nf < 4; ++nf)
#pragma unroll
    for (int ks = 0; ks < K / 32; ++ks)
      bfrag[nf][ks] = *(const short8*)&W[(size_t)(n0 + nf * 16 + lr) * K + ks * 32 + lk];

  f32x4 acc[4][4];
#pragma unroll
  for (int i = 0; i < 4; ++i)
#pragma unroll
    for (int j = 0; j < 4; ++j) acc[i][j] = (f32x4){0.f, 0.f, 0.f, 0.f};

#pragma unroll
  for (int mf = 0; mf < 4; ++mf) {
    int mr = m0 + mf * 16 + lr;
    int mrc = mr < M ? mr : 0;
    short8 afrag[K / 32];
#pragma unroll
    for (int ks = 0; ks < K / 32; ++ks)
      afrag[ks] = *(const short8*)&A[(size_t)mrc * K + ks * 32 + lk];
#pragma unroll
    for (int ks = 0; ks < K / 32; ++ks)
#pragma unroll
      for (int nf = 0; nf < 4; ++nf)
        acc[mf][nf] = MFMA16(afrag[ks], bfrag[nf][ks], acc[mf][nf], 0, 0, 0);
  }

  int cr = (lane >> 4) * 4;
#pragma unroll
  for (int mf = 0; mf < 4; ++mf) {
#pragma unroll
    for (int r = 0; r < 4; ++r) {
      int m = m0 + mf * 16 + cr + r;
      if (m < M) {
#pragma unroll
        for (int nf = 0; nf < 4; ++nf) {
          int n = n0 + nf * 16 + lr;
          float v = acc[mf][nf][r] + bp[nb + nf * 16 + lr];
          C[(size_t)m * HD + n] = f2bf(v);
        }
      }
    }
  }
}

// ---------------- Fused GATv2 per-node aggregate + LN + ELU (+ MLP) ----------------
// One wave per node; lane l owns channels 4l..4l+3 of the 256 (H*HID).
// The 4 sixteen-lane rows ARE the 4 heads: per-lane ssum is already the
// per-head softmax denominator — do NOT sum it across rows (R4 bug).
template <bool LAST>
__global__ __launch_bounds__(256) void gat_kernel(
    const unsigned short* __restrict__ xlr,
    const float* __restrict__ att, const float* __restrict__ bias,
    const float* __restrict__ gamma, const float* __restrict__ beta,
    const int* __restrict__ row_start, const int* __restrict__ csr_src,
    const float* __restrict__ Wh1, const float* __restrict__ bh1,
    const float* __restrict__ Wh2, const float* __restrict__ bh2,
    void* __restrict__ outp, int N) {
  __shared__ float sh[4][96];
  int wid = threadIdx.x >> 6;
  int lane = threadIdx.x & 63;
  int v = blockIdx.x * 4 + wid;
  if (v >= N) return;
  int c0 = 4 * lane;
  int cc = 4 * (lane & 15);

  uint2 ur = *(const uint2*)&xlr[(size_t)v * HD + 256 + c0];
  float xr0 = ubits(ur.x << 16), xr1 = ubits(ur.x & 0xffff0000u);
  float xr2 = ubits(ur.y << 16), xr3 = ubits(ur.y & 0xffff0000u);
  float4 at4 = *(const float4*)&att[c0];

  float sA = 0.f, sB = 0.f;
  float aA0 = 0.f, aA1 = 0.f, aA2 = 0.f, aA3 = 0.f;
  float aB0 = 0.f, aB1 = 0.f, aB2 = 0.f, aB3 = 0.f;

  int rs = __builtin_amdgcn_readfirstlane(row_start[v]);
  int re = __builtin_amdgcn_readfirstlane(row_start[v + 1]);

  auto fetchi = [&](int i) -> uint2 {
    int ic = i < re ? i : re - 1;  // clamp; masked at accumulate
    int s = csr_src[ic];
    return *(const uint2*)&xlr[(size_t)s * HD + c0];
  };
  auto edge = [&](uint2 u, bool valid, float& ss, float& a0, float& a1,
                  float& a2, float& a3) {
    float x0 = ubits(u.x << 16), x1 = ubits(u.x & 0xffff0000u);
    float x2 = ubits(u.y << 16), x3 = ubits(u.y & 0xffff0000u);
    float t0 = x0 + xr0, t1 = x1 + xr1, t2 = x2 + xr2, t3 = x3 + xr3;
    // sum(att*leaky(t)) = 0.6*sum(att*t) + 0.4*sum(att*|t|)
    float p6 = t0 * at4.x;
    p6 = fmaf(t1, at4.y, p6);
    p6 = fmaf(t2, at4.z, p6);
    p6 = fmaf(t3, at4.w, p6);
    float p4 = fabsf(t0) * at4.x;
    p4 = fmaf(fabsf(t1), at4.y, p4);
    p4 = fmaf(fabsf(t2), at4.z, p4);
    p4 = fmaf(fabsf(t3), at4.w, p4);
    float sc = fmaf(0.4f, p4, 0.6f * p6);
    sc = dpp_add<0x121>(sc);  // row_ror:1
    sc = dpp_add<0x122>(sc);  // row_ror:2
    sc = dpp_add<0x124>(sc);  // row_ror:4
    sc = dpp_add<0x128>(sc);  // row_ror:8 -> 16-lane (per-head) sum
    float p = __expf(sc);  // scores O(1): softmax shift not needed
    p = valid ? p : 0.f;
    ss += p;
    a0 = fmaf(p, t0, a0);  // accumulate p*t; undo +xr after loop
    a1 = fmaf(p, t1, a1);
    a2 = fmaf(p, t2, a2);
    a3 = fmaf(p, t3, a3);
  };

  uint2 A0, A1, A2, A3, B0, B1, B2, B3;
  A0 = fetchi(rs); A1 = fetchi(rs + 1); A2 = fetchi(rs + 2); A3 = fetchi(rs + 3);
  int b = rs;
  while (true) {
    int nb = b + 4;
    if (nb < re) { B0 = fetchi(nb); B1 = fetchi(nb + 1); B2 = fetchi(nb + 2); B3 = fetchi(nb + 3); }
    edge(A0, true, sA, aA0, aA1, aA2, aA3);
    edge(A1, b + 1 < re, sB, aB0, aB1, aB2, aB3);
    edge(A2, b + 2 < re, sA, aA0, aA1, aA2, aA3);
    edge(A3, b + 3 < re, sB, aB0, aB1, aB2, aB3);
    b = nb;
    if (b >= re) break;
    nb = b + 4;
    if (nb < re) { A0 = fetchi(nb); A1 = fetchi(nb + 1); A2 = fetchi(nb + 2); A3 = fetchi(nb + 3); }
    edge(B0, true, sA, aA0, aA1, aA2, aA3);
    edge(B1, b + 1 < re, sB, aB0, aB1, aB2, aB3);
    edge(B2, b + 2 < re, sA, aA0, aA1, aA2, aA3);
    edge(B3, b + 3 < re, sB, aB0, aB1, aB2, aB3);
    b = nb;
    if (b >= re) break;
  }

  // per-lane (= per-head) softmax denominator; no cross-row reduction here
  float inv = 1.f / (sA + sB);  // self-loop guarantees > 0

  float am[4] = {aA0 + aB0, aA1 + aB1, aA2 + aB2, aA3 + aB3};
  float xrv[4] = {xr0, xr1, xr2, xr3};
  float hv[4];
#pragma unroll
  for (int j = 0; j < 4; ++j) {
    float a = fmaf(am[j], inv, -xrv[j]);  // normalize per-head, undo +xr
    a += __shfl_xor(a, 16);               // then sum the 4 heads
    a += __shfl_xor(a, 32);
    hv[j] = a;
  }
  float4 bias4 = *(const float4*)&bias[cc];
  hv[0] = 0.25f * hv[0] + bias4.x;
  hv[1] = 0.25f * hv[1] + bias4.y;
  hv[2] = 0.25f * hv[2] + bias4.z;
  hv[3] = 0.25f * hv[3] + bias4.w;
  float psum = hv[0] + hv[1] + hv[2] + hv[3];
  float psq = hv[0] * hv[0] + hv[1] * hv[1] + hv[2] * hv[2] + hv[3] * hv[3];
#pragma unroll
  for (int o = 1; o < 16; o <<= 1) {
    psum += __shfl_xor(psum, o);
    psq += __shfl_xor(psq, o);
  }
  float mean = psum * (1.f / 64.f);
  float var = psq * (1.f / 64.f) - mean * mean;
  float rstd = rsqrtf(var + 1e-5f);
  float4 g4 = *(const float4*)&gamma[cc];
  float4 be4 = *(const float4*)&beta[cc];
  float y[4];
  y[0] = (hv[0] - mean) * rstd * g4.x + be4.x;
  y[1] = (hv[1] - mean) * rstd * g4.y + be4.y;
  y[2] = (hv[2] - mean) * rstd * g4.z + be4.z;
  y[3] = (hv[3] - mean) * rstd * g4.w + be4.w;
#pragma unroll
  for (int j = 0; j < 4; ++j) y[j] = y[j] > 0.f ? y[j] : expm1f(y[j]);

  if (!LAST) {
    if (lane < 16) {
      ushort4 o;
      o.x = f2bf(y[0]); o.y = f2bf(y[1]); o.z = f2bf(y[2]); o.w = f2bf(y[3]);
      *(ushort4*)&((unsigned short*)outp)[(size_t)v * HIDC + cc] = o;
    }
  } else {
    float* out = (float*)outp;
    if (lane < 16) {
      sh[wid][cc + 0] = y[0]; sh[wid][cc + 1] = y[1];
      sh[wid][cc + 2] = y[2]; sh[wid][cc + 3] = y[3];
    }
    if (lane < 32) {  // same-wave LDS ordering; waves independent
      float a = bh1[lane];
      const float* wrow = &Wh1[lane * 64];
#pragma unroll 8
      for (int k = 0; k < 64; ++k) a += sh[wid][k] * wrow[k];
      sh[wid][64 + lane] = fmaxf(a, 0.f);
    }
    if (lane < 2) {
      float o = bh2[lane];
      const float* wrow = &Wh2[lane * 32];
#pragma unroll 8
      for (int k = 0; k < 32; ++k) o += sh[wid][64 + k] * wrow[k];
      out[(size_t)v * 2 + lane] = o;
    }
  }
}

// ---------------- launch ----------------
extern "C" void kernel_launch(void* const* d_in, const int* in_sizes, int n_in,
                              void* d_out, int out_size, void* d_ws, size_t ws_size,
                              hipStream_t stream) {
  const float* x = (const float*)d_in[0];
  const int* ei = (const int*)d_in[1];
  const float* Wl1 = (const float*)d_in[2]; const float* bl1 = (const float*)d_in[3];
  const float* Wr1 = (const float*)d_in[4]; const float* br1 = (const float*)d_in[5];
  const float* att1 = (const float*)d_in[6]; const float* bias1 = (const float*)d_in[7];
  const float* Wl2 = (const float*)d_in[8]; const float* bl2 = (const float*)d_in[9];
  const float* Wr2 = (const float*)d_in[10]; const float* br2 = (const float*)d_in[11];
  const float* att2 = (const float*)d_in[12]; const float* bias2 = (const float*)d_in[13];
  const float* g1 = (const float*)d_in[14]; const float* be1 = (const float*)d_in[15];
  const float* g2 = (const float*)d_in[16]; const float* be2 = (const float*)d_in[17];
  const float* Wh1 = (const float*)d_in[18]; const float* bh1 = (const float*)d_in[19];
  const float* Wh2 = (const float*)d_in[20]; const float* bh2 = (const float*)d_in[21];
  float* out = (float*)d_out;

  int N = in_sizes[0] / 128;
  int E = in_sizes[1] / 2;
  int ET = E + N;

  char* ws = (char*)d_ws;
  size_t off = 0;
  auto alloc = [&](size_t bytes) {
    void* p = ws + off;
    off += (bytes + 255) & ~(size_t)255;
    return p;
  };
  unsigned short* xlr = (unsigned short*)alloc((size_t)N * HD * 2);
  unsigned short* xb  = (unsigned short*)alloc((size_t)N * 128 * 2);
  unsigned short* h1b = (unsigned short*)alloc((size_t)N * HIDC * 2);
  unsigned short* Wc1 = (unsigned short*)alloc((size_t)512 * 128 * 2);
  unsigned short* Wc2 = (unsigned short*)alloc((size_t)512 * 64 * 2);
  int* row_start = (int*)alloc((size_t)(N + 1) * 4);
  int* counts = (int*)alloc((size_t)N * 4);
  int* cursor = (int*)alloc((size_t)N * 4);
  int* csr = (int*)alloc((size_t)ET * 4);

  hipMemsetAsync(counts, 0, (size_t)N * 4, stream);
  hipMemsetAsync(cursor, 0, (size_t)N * 4, stream);

  int eb = (ET + 255) / 256;
  count_kernel<<<eb, 256, 0, stream>>>(ei, E, N, counts);
  scan_kernel<<<1, 1024, 0, stream>>>(counts, row_start, N);
  scatter_kernel<<<eb, 256, 0, stream>>>(ei, E, N, row_start, cursor, csr);

  int n4x = N * 128 / 4;
  int tot4 = n4x + 24576;
  pack_all<<<(tot4 + 255) / 256, 256, 0, stream>>>(x, Wl1, Wr1, Wl2, Wr2,
                                                   xb, Wc1, Wc2, n4x);

  dim3 gg((N + 63) / 64, 2);
  mfma_gemm<128><<<gg, 256, 0, stream>>>(xb, Wc1, bl1, br1, xlr, N);

  int gb = (N + 3) / 4;
  gat_kernel<false><<<gb, 256, 0, stream>>>(xlr, att1, bias1, g1, be1,
                                            row_start, csr, nullptr, nullptr,
                                            nullptr, nullptr, h1b, N);

  mfma_gemm<64><<<gg, 256, 0, stream>>>(h1b, Wc2, bl2, br2, xlr, N);

  gat_kernel<true><<<gb, 256, 0, stream>>>(xlr, att2, bias2, g2, be2,
                                           row_start, csr, Wh1, bh1, Wh2, bh2,
                                           out, N);
}